// Round 1
// baseline (373.799 us; speedup 1.0000x reference)
//
#include <hip/hip_runtime.h>
#include <math.h>

#define KC 24
constexpr int D = 16;
constexpr int B = 4;
constexpr int N = 512 * 1024;          // points per image, 2^19
constexpr float DELTA_VAR = 1.0f;
constexpr float DELTA_DIST = 2.0f;

// Workspace layout (floats):
//   g_sums: [B*KC][D]   = 1536
//   g_cnt : [B*KC]      = 96
//   g_hv  : [B*KC]      = 96

// ---------------- Pass 1: per-cluster sums + counts ----------------
__global__ __launch_bounds__(256) void k_sums(const float* __restrict__ data,
                                              const int* __restrict__ labels,
                                              float* __restrict__ g_sums,
                                              float* __restrict__ g_cnt) {
    __shared__ float s_sum[KC * 17];   // +1 pad: seg*16 strides alias to 2 banks otherwise
    __shared__ float s_cnt[KC];
    const int t = threadIdx.x;
    for (int i = t; i < KC * 17; i += 256) s_sum[i] = 0.f;
    if (t < KC) s_cnt[t] = 0.f;
    __syncthreads();

    const int gid = blockIdx.x * 256 + t;
    const int p0  = gid * 4;                 // 4 consecutive points; block stays in one image
    const int b   = p0 >> 19;
    const int n0  = p0 & (N - 1);

    const int4 lab = *(const int4*)(labels + p0);
    const float* dbase = data + (b * D) * (size_t)N + n0;

    for (int d = 0; d < D; ++d) {
        float4 v = *(const float4*)(dbase + d * (size_t)N);
        atomicAdd(&s_sum[lab.x * 17 + d], v.x);
        atomicAdd(&s_sum[lab.y * 17 + d], v.y);
        atomicAdd(&s_sum[lab.z * 17 + d], v.z);
        atomicAdd(&s_sum[lab.w * 17 + d], v.w);
    }
    atomicAdd(&s_cnt[lab.x], 1.f);
    atomicAdd(&s_cnt[lab.y], 1.f);
    atomicAdd(&s_cnt[lab.z], 1.f);
    atomicAdd(&s_cnt[lab.w], 1.f);
    __syncthreads();

    for (int i = t; i < KC * D + KC; i += 256) {
        if (i < KC * D) {
            int c = i >> 4, d = i & 15;
            atomicAdd(&g_sums[(b * KC + c) * D + d], s_sum[c * 17 + d]);
        } else {
            int c = i - KC * D;
            atomicAdd(&g_cnt[b * KC + c], s_cnt[c]);
        }
    }
}

// ---------------- Pass 2: hinged variance per point ----------------
__global__ __launch_bounds__(256) void k_var(const float* __restrict__ data,
                                             const int* __restrict__ labels,
                                             const float* __restrict__ g_sums,
                                             const float* __restrict__ g_cnt,
                                             float* __restrict__ g_hv) {
    __shared__ float s_c[KC * 17];
    __shared__ float s_hv[KC];
    const int t = threadIdx.x;

    const int gid = blockIdx.x * 256 + t;
    const int p0  = gid * 4;
    const int b   = p0 >> 19;
    const int n0  = p0 & (N - 1);

    for (int i = t; i < KC * D; i += 256) {
        int c = i >> 4, d = i & 15;
        s_c[c * 17 + d] = g_sums[(b * KC + c) * D + d] / g_cnt[b * KC + c];
    }
    if (t < KC) s_hv[t] = 0.f;
    __syncthreads();

    const int4 lab = *(const int4*)(labels + p0);
    const float* dbase = data + (b * D) * (size_t)N + n0;

    float sq0 = 0.f, sq1 = 0.f, sq2 = 0.f, sq3 = 0.f;
    for (int d = 0; d < D; ++d) {
        float4 v = *(const float4*)(dbase + d * (size_t)N);
        float t0 = v.x - s_c[lab.x * 17 + d]; sq0 += t0 * t0;
        float t1 = v.y - s_c[lab.y * 17 + d]; sq1 += t1 * t1;
        float t2 = v.z - s_c[lab.z * 17 + d]; sq2 += t2 * t2;
        float t3 = v.w - s_c[lab.w * 17 + d]; sq3 += t3 * t3;
    }
    float h;
    h = fmaxf(sqrtf(sq0) - DELTA_VAR, 0.f); atomicAdd(&s_hv[lab.x], h * h);
    h = fmaxf(sqrtf(sq1) - DELTA_VAR, 0.f); atomicAdd(&s_hv[lab.y], h * h);
    h = fmaxf(sqrtf(sq2) - DELTA_VAR, 0.f); atomicAdd(&s_hv[lab.z], h * h);
    h = fmaxf(sqrtf(sq3) - DELTA_VAR, 0.f); atomicAdd(&s_hv[lab.w], h * h);
    __syncthreads();

    if (t < KC) atomicAdd(&g_hv[b * KC + t], s_hv[t]);
}

// ---------------- Finalize: var + dist + reg -> scalar ----------------
__global__ __launch_bounds__(128) void k_final(const float* __restrict__ g_sums,
                                               const float* __restrict__ g_cnt,
                                               const float* __restrict__ g_hv,
                                               float* __restrict__ out) {
    __shared__ float s_c[B * KC * 17];
    __shared__ float s_red[2];
    const int t = threadIdx.x;

    float acc = 0.f;  // var + reg contributions
    if (t < B * KC) {
        float cnt = g_cnt[t];
        float ns = 0.f;
        for (int d = 0; d < D; ++d) {
            float c = g_sums[t * D + d] / cnt;
            s_c[t * 17 + d] = c;
            ns += c * c;
        }
        acc = g_hv[t] / cnt + sqrtf(ns) / (float)KC;
    }
    __syncthreads();

    float dacc = 0.f;  // raw sum of hd over [B,K,K] incl. diagonal (= (2-0)^2 = 4 each)
    for (int idx = t; idx < B * KC * KC; idx += 128) {
        int b = idx / (KC * KC);
        int r = idx % (KC * KC);
        int i = r / KC, j = r % KC;
        float hd;
        if (i == j) {
            hd = DELTA_DIST * DELTA_DIST;
        } else {
            const float* ci = &s_c[(b * KC + i) * 17];
            const float* cj = &s_c[(b * KC + j) * 17];
            float sq = 0.f;
            for (int d = 0; d < D; ++d) { float df = ci[d] - cj[d]; sq += df * df; }
            float hh = fmaxf(DELTA_DIST - sqrtf(sq), 0.f);
            hd = hh * hh;
        }
        dacc += hd;
    }
    float total = acc + dacc / (2.f * KC * (KC - 1));

    for (int o = 32; o > 0; o >>= 1) total += __shfl_down(total, o, 64);
    if ((t & 63) == 0) s_red[t >> 6] = total;
    __syncthreads();
    if (t == 0) out[0] = (s_red[0] + s_red[1]) / (float)B;
}

extern "C" void kernel_launch(void* const* d_in, const int* in_sizes, int n_in,
                              void* d_out, int out_size, void* d_ws, size_t ws_size,
                              hipStream_t stream) {
    const float* data  = (const float*)d_in[0];
    const int* labels  = (const int*)d_in[1];
    float* ws = (float*)d_ws;
    float* g_sums = ws;                    // B*KC*D = 1536
    float* g_cnt  = ws + B * KC * D;       // 96
    float* g_hv   = g_cnt + B * KC;        // 96

    hipMemsetAsync(d_ws, 0, (B * KC * D + 2 * B * KC) * sizeof(float), stream);

    const int blocks = (B * N) / (256 * 4);  // 2048, each block = 1024 pts in one image
    k_sums<<<blocks, 256, 0, stream>>>(data, labels, g_sums, g_cnt);
    k_var <<<blocks, 256, 0, stream>>>(data, labels, g_sums, g_cnt, g_hv);
    k_final<<<1, 128, 0, stream>>>(g_sums, g_cnt, g_hv, (float*)d_out);
}

// Round 2
// 364.415 us; speedup vs baseline: 1.0258x; 1.0258x over previous
//
#include <hip/hip_runtime.h>
#include <math.h>

#define KC 24
constexpr int D = 16;
constexpr int B = 4;
constexpr int N = 512 * 1024;          // points per image, 2^19
constexpr float DELTA_VAR = 1.0f;
constexpr float DELTA_DIST = 2.0f;

constexpr int REP = 8;                 // LDS accumulator replicas (replica = lane&7)
constexpr int RS  = KC * 17;           // 408 words per sum replica (17-pad rows)
constexpr int CS  = 33;                // count/hv replica stride (bank spread)
constexpr int BLOCKS = 1024;           // 2048 consecutive points per block, within one image
constexpr int ITERS  = (B * N) / (BLOCKS * 256 * 4);   // = 2

// Workspace (floats): g_sums [B*KC*D]=1536 | g_cnt [B*KC]=96 | g_hv [B*KC]=96

// ---------------- Pass 1: per-cluster sums + counts ----------------
__global__ __launch_bounds__(256) void k_sums(const float* __restrict__ data,
                                              const int* __restrict__ labels,
                                              float* __restrict__ g_sums,
                                              float* __restrict__ g_cnt) {
    __shared__ float s_sum[REP * RS];      // 13 KB
    __shared__ float s_cnt[REP * CS];
    const int t = threadIdx.x;
    for (int i = t; i < REP * RS; i += 256) s_sum[i] = 0.f;
    for (int i = t; i < REP * CS; i += 256) s_cnt[i] = 0.f;
    __syncthreads();

    const int chunk = blockIdx.x * (256 * 4 * ITERS);
    const int b     = chunk >> 19;
    const int rbase = (t & 7) * RS;
    const int cbase = (t & 7) * CS;

    for (int it = 0; it < ITERS; ++it) {
        const int p0 = chunk + it * 1024 + t * 4;
        const int n0 = p0 & (N - 1);
        const int4 lab = *(const int4*)(labels + p0);
        const float* dbase = data + (size_t)(b * D) * N + n0;

        float4 v[D];                        // prefetch ALL dims: 16 loads in flight
#pragma unroll
        for (int d = 0; d < D; ++d) v[d] = *(const float4*)(dbase + (size_t)d * N);

#pragma unroll
        for (int d = 0; d < D; ++d) {
            atomicAdd(&s_sum[rbase + lab.x * 17 + d], v[d].x);
            atomicAdd(&s_sum[rbase + lab.y * 17 + d], v[d].y);
            atomicAdd(&s_sum[rbase + lab.z * 17 + d], v[d].z);
            atomicAdd(&s_sum[rbase + lab.w * 17 + d], v[d].w);
        }
        atomicAdd(&s_cnt[cbase + lab.x], 1.f);
        atomicAdd(&s_cnt[cbase + lab.y], 1.f);
        atomicAdd(&s_cnt[cbase + lab.z], 1.f);
        atomicAdd(&s_cnt[cbase + lab.w], 1.f);
    }
    __syncthreads();

    for (int i = t; i < KC * D + KC; i += 256) {
        if (i < KC * D) {
            int c = i >> 4, d = i & 15;
            float s = 0.f;
#pragma unroll
            for (int r = 0; r < REP; ++r) s += s_sum[r * RS + c * 17 + d];
            atomicAdd(&g_sums[b * (KC * D) + i], s);
        } else {
            int c = i - KC * D;
            float s = 0.f;
#pragma unroll
            for (int r = 0; r < REP; ++r) s += s_cnt[r * CS + c];
            atomicAdd(&g_cnt[b * KC + c], s);
        }
    }
}

// ---------------- Pass 2: hinged variance per point ----------------
__global__ __launch_bounds__(256) void k_var(const float* __restrict__ data,
                                             const int* __restrict__ labels,
                                             const float* __restrict__ g_sums,
                                             const float* __restrict__ g_cnt,
                                             float* __restrict__ g_hv) {
    __shared__ float s_c[KC * 20];         // 20-float rows: b128-aligned, bank-spread
    __shared__ float s_hv[REP * CS];
    const int t = threadIdx.x;
    const int chunk = blockIdx.x * (256 * 4 * ITERS);
    const int b     = chunk >> 19;

    for (int i = t; i < KC * D; i += 256) {
        int c = i >> 4, d = i & 15;
        s_c[c * 20 + d] = g_sums[b * (KC * D) + i] / g_cnt[b * KC + c];
    }
    for (int i = t; i < REP * CS; i += 256) s_hv[i] = 0.f;
    __syncthreads();

    const int cbase = (t & 7) * CS;

    for (int it = 0; it < ITERS; ++it) {
        const int p0 = chunk + it * 1024 + t * 4;
        const int n0 = p0 & (N - 1);
        const int4 lab = *(const int4*)(labels + p0);
        const float* dbase = data + (size_t)(b * D) * N + n0;

        float4 v[D];
#pragma unroll
        for (int d = 0; d < D; ++d) v[d] = *(const float4*)(dbase + (size_t)d * N);

#define HVPT(LBL, COMP) do {                                                 \
        const float* cp = &s_c[(LBL) * 20];                                  \
        float4 ca = *(const float4*)(cp);                                    \
        float4 cb = *(const float4*)(cp + 4);                                \
        float4 cc = *(const float4*)(cp + 8);                                \
        float4 cd = *(const float4*)(cp + 12);                               \
        float sq = 0.f, df;                                                  \
        df = v[0].COMP  - ca.x; sq += df * df;                               \
        df = v[1].COMP  - ca.y; sq += df * df;                               \
        df = v[2].COMP  - ca.z; sq += df * df;                               \
        df = v[3].COMP  - ca.w; sq += df * df;                               \
        df = v[4].COMP  - cb.x; sq += df * df;                               \
        df = v[5].COMP  - cb.y; sq += df * df;                               \
        df = v[6].COMP  - cb.z; sq += df * df;                               \
        df = v[7].COMP  - cb.w; sq += df * df;                               \
        df = v[8].COMP  - cc.x; sq += df * df;                               \
        df = v[9].COMP  - cc.y; sq += df * df;                               \
        df = v[10].COMP - cc.z; sq += df * df;                               \
        df = v[11].COMP - cc.w; sq += df * df;                               \
        df = v[12].COMP - cd.x; sq += df * df;                               \
        df = v[13].COMP - cd.y; sq += df * df;                               \
        df = v[14].COMP - cd.z; sq += df * df;                               \
        df = v[15].COMP - cd.w; sq += df * df;                               \
        float h = fmaxf(sqrtf(sq) - DELTA_VAR, 0.f);                         \
        atomicAdd(&s_hv[cbase + (LBL)], h * h);                              \
    } while (0)

        HVPT(lab.x, x);
        HVPT(lab.y, y);
        HVPT(lab.z, z);
        HVPT(lab.w, w);
#undef HVPT
    }
    __syncthreads();

    if (t < KC) {
        float s = 0.f;
#pragma unroll
        for (int r = 0; r < REP; ++r) s += s_hv[r * CS + t];
        atomicAdd(&g_hv[b * KC + t], s);
    }
}

// ---------------- Finalize: var + dist + reg -> scalar ----------------
__global__ __launch_bounds__(128) void k_final(const float* __restrict__ g_sums,
                                               const float* __restrict__ g_cnt,
                                               const float* __restrict__ g_hv,
                                               float* __restrict__ out) {
    __shared__ float s_c[B * KC * 17];
    __shared__ float s_red[2];
    const int t = threadIdx.x;

    float acc = 0.f;  // var + reg contributions
    if (t < B * KC) {
        float cnt = g_cnt[t];
        float ns = 0.f;
        for (int d = 0; d < D; ++d) {
            float c = g_sums[t * D + d] / cnt;
            s_c[t * 17 + d] = c;
            ns += c * c;
        }
        acc = g_hv[t] / cnt + sqrtf(ns) / (float)KC;
    }
    __syncthreads();

    float dacc = 0.f;  // raw sum over [B,K,K] incl. diagonal (= delta_dist^2 each)
    for (int idx = t; idx < B * KC * KC; idx += 128) {
        int b = idx / (KC * KC);
        int r = idx % (KC * KC);
        int i = r / KC, j = r % KC;
        float hd;
        if (i == j) {
            hd = DELTA_DIST * DELTA_DIST;
        } else {
            const float* ci = &s_c[(b * KC + i) * 17];
            const float* cj = &s_c[(b * KC + j) * 17];
            float sq = 0.f;
            for (int d = 0; d < D; ++d) { float df = ci[d] - cj[d]; sq += df * df; }
            float hh = fmaxf(DELTA_DIST - sqrtf(sq), 0.f);
            hd = hh * hh;
        }
        dacc += hd;
    }
    float total = acc + dacc / (2.f * KC * (KC - 1));

    for (int o = 32; o > 0; o >>= 1) total += __shfl_down(total, o, 64);
    if ((t & 63) == 0) s_red[t >> 6] = total;
    __syncthreads();
    if (t == 0) out[0] = (s_red[0] + s_red[1]) / (float)B;
}

extern "C" void kernel_launch(void* const* d_in, const int* in_sizes, int n_in,
                              void* d_out, int out_size, void* d_ws, size_t ws_size,
                              hipStream_t stream) {
    const float* data  = (const float*)d_in[0];
    const int* labels  = (const int*)d_in[1];
    float* ws = (float*)d_ws;
    float* g_sums = ws;                    // 1536
    float* g_cnt  = ws + B * KC * D;       // 96
    float* g_hv   = g_cnt + B * KC;        // 96

    hipMemsetAsync(d_ws, 0, (B * KC * D + 2 * B * KC) * sizeof(float), stream);

    k_sums<<<BLOCKS, 256, 0, stream>>>(data, labels, g_sums, g_cnt);
    k_var <<<BLOCKS, 256, 0, stream>>>(data, labels, g_sums, g_cnt, g_hv);
    k_final<<<1, 128, 0, stream>>>(g_sums, g_cnt, g_hv, (float*)d_out);
}

// Round 3
// 356.244 us; speedup vs baseline: 1.0493x; 1.0229x over previous
//
#include <hip/hip_runtime.h>
#include <math.h>

#define KC 24
constexpr int D = 16;
constexpr int B = 4;
constexpr int N = 512 * 1024;          // points per image, 2^19
constexpr float DELTA_VAR = 1.0f;
constexpr float DELTA_DIST = 2.0f;

constexpr int REP = 8;                 // LDS accumulator replicas (replica = lane&7)
constexpr int RS  = KC * 17;           // 408 words per sum replica
constexpr int CS  = 33;
constexpr int PTS = 1024;              // points per block
constexpr int BLOCKS = (B * N) / PTS;  // 2048 -> 8 blocks/CU, 32 waves (occupancy cap)

// ws (floats): g_sums [B*KC*D]=1536 | g_cnt [B*KC]=96 | g_varp [64]

// ---------------- Pass 1: per-cluster sums + counts (plane-sequential) ----------------
__global__ __launch_bounds__(256) void k_sums(const float* __restrict__ data,
                                              const int* __restrict__ labels,
                                              float* __restrict__ g_sums,
                                              float* __restrict__ g_cnt) {
    __shared__ float s_sum[REP * RS];      // 13 KB
    __shared__ float s_cnt[REP * CS];
    const int t = threadIdx.x;
    for (int i = t; i < REP * RS; i += 256) s_sum[i] = 0.f;
    for (int i = t; i < REP * CS; i += 256) s_cnt[i] = 0.f;
    __syncthreads();

    const int chunk = blockIdx.x * PTS;
    const int b     = chunk >> 19;
    const int n0    = (chunk & (N - 1)) + t * 4;

    const int4 lab = *(const int4*)(labels + chunk + t * 4);  // labels of THIS thread's 4 points
    const int rbase = (t & 7) * RS;
    const int ax = rbase + lab.x * 17;
    const int ay = rbase + lab.y * 17;
    const int az = rbase + lab.z * 17;
    const int aw = rbase + lab.w * 17;

    const float* base = data + (size_t)(b * D) * N + n0;
    float4 cur = *(const float4*)(base);           // rolling 1-ahead prefetch
#pragma unroll
    for (int d = 0; d < D; ++d) {
        float4 nxt;
        if (d < D - 1) nxt = *(const float4*)(base + (size_t)(d + 1) * N);
        atomicAdd(&s_sum[ax + d], cur.x);
        atomicAdd(&s_sum[ay + d], cur.y);
        atomicAdd(&s_sum[az + d], cur.z);
        atomicAdd(&s_sum[aw + d], cur.w);
        cur = nxt;
    }
    const int cbase = (t & 7) * CS;
    atomicAdd(&s_cnt[cbase + lab.x], 1.f);
    atomicAdd(&s_cnt[cbase + lab.y], 1.f);
    atomicAdd(&s_cnt[cbase + lab.z], 1.f);
    atomicAdd(&s_cnt[cbase + lab.w], 1.f);
    __syncthreads();

    // epilogue: rotated order so blocks don't convoy on the same global address
    const int rot = (blockIdx.x * 131) & 255;
    for (int i = t; i < KC * D; i += 256) {
        int j = (i + rot) % (KC * D);
        int c = j >> 4, d = j & 15;
        float s = 0.f;
#pragma unroll
        for (int r = 0; r < REP; ++r) s += s_sum[r * RS + c * 17 + d];
        atomicAdd(&g_sums[b * (KC * D) + j], s);
    }
    if (t < KC) {
        float s = 0.f;
#pragma unroll
        for (int r = 0; r < REP; ++r) s += s_cnt[r * CS + t];
        atomicAdd(&g_cnt[b * KC + t], s);
    }
}

// ---------------- Pass 2: hinged variance — NO LDS atomics ----------------
// var_sum = sum_n h_n^2 / cnt[lab_n]  (global scalar; no per-cluster binning needed)
__global__ __launch_bounds__(256) void k_var(const float* __restrict__ data,
                                             const int* __restrict__ labels,
                                             const float* __restrict__ g_sums,
                                             const float* __restrict__ g_cnt,
                                             float* __restrict__ g_varp) {
    __shared__ float s_c[KC * 17];
    __shared__ float s_ic[KC];
    __shared__ float s_part[4];
    const int t = threadIdx.x;
    const int chunk = blockIdx.x * PTS;
    const int b     = chunk >> 19;
    const int n0    = (chunk & (N - 1)) + t * 4;

    for (int i = t; i < KC * D; i += 256) {
        int c = i >> 4, d = i & 15;
        s_c[c * 17 + d] = g_sums[b * (KC * D) + i] / g_cnt[b * KC + c];
    }
    if (t < KC) s_ic[t] = 1.f / g_cnt[b * KC + t];
    __syncthreads();

    const int4 lab = *(const int4*)(labels + chunk + t * 4);
    const int ax = lab.x * 17, ay = lab.y * 17, az = lab.z * 17, aw = lab.w * 17;

    const float* base = data + (size_t)(b * D) * N + n0;
    float4 acc = {0.f, 0.f, 0.f, 0.f};
    float4 cur = *(const float4*)(base);
#pragma unroll
    for (int d = 0; d < D; ++d) {
        float4 nxt;
        if (d < D - 1) nxt = *(const float4*)(base + (size_t)(d + 1) * N);
        float df;
        df = cur.x - s_c[ax + d]; acc.x += df * df;
        df = cur.y - s_c[ay + d]; acc.y += df * df;
        df = cur.z - s_c[az + d]; acc.z += df * df;
        df = cur.w - s_c[aw + d]; acc.w += df * df;
        cur = nxt;
    }
    float h, hsum;
    h = fmaxf(sqrtf(acc.x) - DELTA_VAR, 0.f); hsum  = h * h * s_ic[lab.x];
    h = fmaxf(sqrtf(acc.y) - DELTA_VAR, 0.f); hsum += h * h * s_ic[lab.y];
    h = fmaxf(sqrtf(acc.z) - DELTA_VAR, 0.f); hsum += h * h * s_ic[lab.z];
    h = fmaxf(sqrtf(acc.w) - DELTA_VAR, 0.f); hsum += h * h * s_ic[lab.w];

    for (int o = 32; o > 0; o >>= 1) hsum += __shfl_down(hsum, o, 64);
    if ((t & 63) == 0) s_part[t >> 6] = hsum;
    __syncthreads();
    if (t == 0)
        atomicAdd(&g_varp[blockIdx.x & 63],
                  s_part[0] + s_part[1] + s_part[2] + s_part[3]);
}

// ---------------- Finalize: var + dist + reg -> scalar ----------------
__global__ __launch_bounds__(128) void k_final(const float* __restrict__ g_sums,
                                               const float* __restrict__ g_cnt,
                                               const float* __restrict__ g_varp,
                                               float* __restrict__ out) {
    __shared__ float s_c[B * KC * 17];
    __shared__ float s_red[2];
    const int t = threadIdx.x;

    float acc = 0.f;
    if (t < B * KC) {               // reg term + center build
        float cnt = g_cnt[t];
        float ns = 0.f;
        for (int d = 0; d < D; ++d) {
            float c = g_sums[t * D + d] / cnt;
            s_c[t * 17 + d] = c;
            ns += c * c;
        }
        acc = sqrtf(ns) / (float)KC;
    }
    if (t < 64) acc += g_varp[t];   // var term partials
    __syncthreads();

    float dacc = 0.f;  // raw sum over [B,K,K] incl. diagonal (= delta_dist^2 each)
    for (int idx = t; idx < B * KC * KC; idx += 128) {
        int b = idx / (KC * KC);
        int r = idx % (KC * KC);
        int i = r / KC, j = r % KC;
        float hd;
        if (i == j) {
            hd = DELTA_DIST * DELTA_DIST;
        } else {
            const float* ci = &s_c[(b * KC + i) * 17];
            const float* cj = &s_c[(b * KC + j) * 17];
            float sq = 0.f;
            for (int d = 0; d < D; ++d) { float df = ci[d] - cj[d]; sq += df * df; }
            float hh = fmaxf(DELTA_DIST - sqrtf(sq), 0.f);
            hd = hh * hh;
        }
        dacc += hd;
    }
    float total = acc + dacc / (2.f * KC * (KC - 1));

    for (int o = 32; o > 0; o >>= 1) total += __shfl_down(total, o, 64);
    if ((t & 63) == 0) s_red[t >> 6] = total;
    __syncthreads();
    if (t == 0) out[0] = (s_red[0] + s_red[1]) / (float)B;
}

extern "C" void kernel_launch(void* const* d_in, const int* in_sizes, int n_in,
                              void* d_out, int out_size, void* d_ws, size_t ws_size,
                              hipStream_t stream) {
    const float* data  = (const float*)d_in[0];
    const int* labels  = (const int*)d_in[1];
    float* ws = (float*)d_ws;
    float* g_sums = ws;                    // 1536
    float* g_cnt  = ws + B * KC * D;       // 96
    float* g_varp = g_cnt + B * KC;        // 64

    hipMemsetAsync(d_ws, 0, (B * KC * D + B * KC + 64) * sizeof(float), stream);

    k_sums<<<BLOCKS, 256, 0, stream>>>(data, labels, g_sums, g_cnt);
    k_var <<<BLOCKS, 256, 0, stream>>>(data, labels, g_sums, g_cnt, g_varp);
    k_final<<<1, 128, 0, stream>>>(g_sums, g_cnt, g_varp, (float*)d_out);
}